// Round 5
// baseline (112.771 us; speedup 1.0000x reference)
//
#include <hip/hip_runtime.h>
#include <math.h>

// Problem constants (fixed by reference)
#define Dn   1024
#define Tn   8
#define Bn   4096
#define NCn  64
#define V_RESET   (-0.1f)
#define REFRAC_T  2.0f
#define V_SCALE   0.0625f   // 1/(D/NC) = 1/16, exact power of 2

// Native clang vector type: required by __builtin_nontemporal_store
// (HIP's float4 is a class and is rejected).
typedef float f32x4 __attribute__((ext_vector_type(4)));

__device__ __forceinline__ float sigm(float x) {
    return 1.0f / (1.0f + expf(-x));
}

__device__ __forceinline__ float readlane_f(float x, int l) {
    return __int_as_float(__builtin_amdgcn_readlane(__float_as_int(x), l));
}

// One wave (64 lanes) per batch row. Lane l owns elements d = 256*j + 4*l + i
// (j=0..3, i=0..3): float4-coalesced, and cid(d) = (4l+i)&63 is j-invariant so
// the cluster segment-sum needs only 2 shfl_xor per i. Whole T-loop is
// barrier-free; state lives in registers.
//
// Occupancy pin (round-4 lesson): __launch_bounds__(256,4) only sets a MIN
// waves/EU; the backend still targeted 8 waves/EU, allocated 64 VGPRs, and
// spilled ~26 dwords/thread (= the observed +104 MB WRITE_SIZE, VGPR_Count=64).
// amdgpu_waves_per_eu(4,4) pins min=max=4 -> 128-VGPR budget, demand ~100,
// zero spill, grid (1024 blocks = 4 waves/SIMD) still fully co-resident.
__global__ __launch_bounds__(256)
__attribute__((amdgpu_waves_per_eu(4, 4)))
void snn_fwd(
    const float* __restrict__ cur_in,   // (T,B,D)
    const float* __restrict__ thr,      // (D,)
    const float* __restrict__ bm_raw,   // scalar
    const float* __restrict__ bs_raw,   // scalar
    const float* __restrict__ nw,       // (NC,NC)
    const float* __restrict__ gain,     // (NC,)
    float* __restrict__ out)            // spikes (T,B,D) then v_trace (T,B,D)
{
    __shared__ float WT[NCn * NCn];     // WT[k*64+c] = sigmoid(nw[c][k]) (transposed)

    const int tid  = threadIdx.x;
    const int lane = tid & 63;
    const int wv   = tid >> 6;
    const int b    = (blockIdx.x << 2) + wv;
    const int col0 = lane << 2;         // 4*lane

    // Issue t=0 input loads FIRST so their latency hides under W prep.
    float cu[16];
    {
        const size_t base0 = (size_t)b * Dn;
        #pragma unroll
        for (int j = 0; j < 4; ++j) {
            const float4 c4 = *reinterpret_cast<const float4*>(&cur_in[base0 + j * 256 + col0]);
            cu[j*4+0] = c4.x; cu[j*4+1] = c4.y; cu[j*4+2] = c4.z; cu[j*4+3] = c4.w;
        }
    }
    float th[16];
    #pragma unroll
    for (int j = 0; j < 4; ++j) {
        const float4 t4 = *reinterpret_cast<const float4*>(&thr[j * 256 + col0]);
        th[j*4+0] = t4.x; th[j*4+1] = t4.y; th[j*4+2] = t4.z; th[j*4+3] = t4.w;
    }

    // Per-block W prep: 16 sigmoids/thread, once.
    for (int e = tid; e < NCn * NCn; e += 256) {
        const int k = e >> 6, c = e & 63;
        WT[e] = sigm(nw[c * NCn + k]);
    }
    const float bm  = sigm(bm_raw[0]);
    const float bs  = sigm(bs_raw[0]);
    const float bm1 = 1.0f - bm;
    const float g   = gain[lane];

    float v[16], isyn[16], rf[16];
    #pragma unroll
    for (int e = 0; e < 16; ++e) { v[e] = 0.0f; isyn[e] = 0.0f; rf[e] = 0.0f; }

    __syncthreads();

    float* __restrict__ outS = out;
    float* __restrict__ outV = out + (size_t)Tn * Bn * Dn;

    #pragma unroll
    for (int t = 0; t < Tn; ++t) {
        const size_t base = ((size_t)t * Bn + b) * Dn;

        float cfp[4] = {0.0f, 0.0f, 0.0f, 0.0f};

        // Phase 1: state update + spike + store. cu[] is fully consumed here.
        #pragma unroll
        for (int j = 0; j < 4; ++j) {
            float s[4];
            #pragma unroll
            for (int i = 0; i < 4; ++i) {
                const int e = j * 4 + i;
                // i_syn = beta_s*i_syn + cur   (unfused mul+add, mirrors XLA)
                isyn[e] = __fadd_rn(__fmul_rn(bs, isyn[e]), cu[e]);
                // v_mem = refrac>0 ? V_RESET : beta_m*v + (1-beta_m)*i_syn
                float vn = __fadd_rn(__fmul_rn(bm, v[e]), __fmul_rn(bm1, isyn[e]));
                vn = (rf[e] > 0.0f) ? V_RESET : vn;
                const float sp = (vn >= th[e]) ? 1.0f : 0.0f;
                cfp[i] += sp;    // spike counts: small ints, exact in fp32
                s[i] = sp;
                // post-spike membrane + refractory update (off critical path)
                v[e]  = __fsub_rn(vn, __fmul_rn(sp, th[e]));
                rf[e] = (sp > 0.0f) ? REFRAC_T : fmaxf(rf[e] - 1.0f, 0.0f);
            }
            f32x4 s4; s4.x = s[0]; s4.y = s[1]; s4.z = s[2]; s4.w = s[3];
            f32x4 v4; v4.x = v[j*4+0]; v4.y = v[j*4+1]; v4.z = v[j*4+2]; v4.w = v[j*4+3];
            // Outputs are never re-read: nontemporal keeps input L3-resident.
            __builtin_nontemporal_store(s4, reinterpret_cast<f32x4*>(&outS[base + j * 256 + col0]));
            __builtin_nontemporal_store(v4, reinterpret_cast<f32x4*>(&outV[base + j * 256 + col0]));
        }

        // Phase 2: prefetch t+1's input into the now-free cu[] regs. Its
        // latency hides under phase 3 (reduce/dot/cascade) + wave TLP.
        if (t + 1 < Tn) {
            const size_t basen = ((size_t)(t + 1) * Bn + b) * Dn;
            #pragma unroll
            for (int j = 0; j < 4; ++j) {
                const float4 c4 = *reinterpret_cast<const float4*>(&cur_in[basen + j * 256 + col0]);
                cu[j*4+0] = c4.x; cu[j*4+1] = c4.y; cu[j*4+2] = c4.z; cu[j*4+3] = c4.w;
            }
        }

        // Phase 3: cluster_fire reduce (lanes l^16, l^32 share cid set),
        // *= 1/16 (exact). cfp[i] on lane l is cf[cluster 4*(l&15)+i].
        #pragma unroll
        for (int i = 0; i < 4; ++i) {
            cfp[i] += __shfl_xor(cfp[i], 16, 64);
            cfp[i] += __shfl_xor(cfp[i], 32, 64);
            cfp[i] *= V_SCALE;
        }

        // neighbor[c=lane] = (sum_k cf[k] * W[c][k]) * gain[c]
        // cf[k] broadcast from lane k>>2, register k&3 via v_readlane.
        // 4 independent accumulator chains (dep depth 16 instead of 64).
        float a0 = 0.0f, a1 = 0.0f, a2 = 0.0f, a3 = 0.0f;
        #pragma unroll
        for (int k = 0; k < 64; k += 4) {
            const int src = k >> 2;
            a0 = fmaf(readlane_f(cfp[0], src), WT[(k+0) * 64 + lane], a0);
            a1 = fmaf(readlane_f(cfp[1], src), WT[(k+1) * 64 + lane], a1);
            a2 = fmaf(readlane_f(cfp[2], src), WT[(k+2) * 64 + lane], a2);
            a3 = fmaf(readlane_f(cfp[3], src), WT[(k+3) * 64 + lane], a3);
        }
        const float nb = __fmul_rn(__fadd_rn(__fadd_rn(a0, a1), __fadd_rn(a2, a3)), g);

        // cascade gather: this lane's 4 cids, then fold into i_syn for t+1
        #pragma unroll
        for (int i = 0; i < 4; ++i) {
            const float nbi = __shfl(nb, (col0 + i) & 63, 64);
            #pragma unroll
            for (int j = 0; j < 4; ++j) {
                isyn[j*4 + i] = __fadd_rn(isyn[j*4 + i], nbi);
            }
        }
    }
}

extern "C" void kernel_launch(void* const* d_in, const int* in_sizes, int n_in,
                              void* d_out, int out_size, void* d_ws, size_t ws_size,
                              hipStream_t stream) {
    const float* cur_in = (const float*)d_in[0];
    const float* thr    = (const float*)d_in[1];
    const float* bm_raw = (const float*)d_in[2];
    const float* bs_raw = (const float*)d_in[3];
    const float* nw     = (const float*)d_in[4];
    const float* gain   = (const float*)d_in[5];
    float* out = (float*)d_out;

    // 4 rows per block (one wave each) -> B/4 = 1024 blocks of 256 threads.
    dim3 grid(Bn / 4), block(256);
    snn_fwd<<<grid, block, 0, stream>>>(cur_in, thr, bm_raw, bs_raw, nw, gain, out);
}

// Round 6
// 65.439 us; speedup vs baseline: 1.7233x; 1.7233x over previous
//
#include <hip/hip_runtime.h>
#include <math.h>

// Problem constants (fixed by reference)
#define Dn   1024
#define Tn   8
#define Bn   4096
#define NCn  64
#define V_RESET   (-0.1f)
#define REFRAC_T  2.0f
#define V_SCALE   0.0625f   // 1/(D/NC) = 1/16, exact power of 2

// Native clang vector type: required by __builtin_nontemporal_store
// (HIP's float4 is a class and is rejected).
typedef float f32x4 __attribute__((ext_vector_type(4)));

__device__ __forceinline__ float sigm(float x) {
    return 1.0f / (1.0f + expf(-x));
}

__device__ __forceinline__ float readlane_f(float x, int l) {
    return __int_as_float(__builtin_amdgcn_readlane(__float_as_int(x), l));
}

// TWO waves per batch row (rounds 2-5 lesson): the backend insists on a
// 64-VGPR / 8-waves-per-EU schedule regardless of launch_bounds or
// amdgpu_waves_per_eu pins; the 1-wave-per-row layout needs ~100 live floats
// -> ~13 slots spilled and rewritten EVERY timestep (= the persistent
// +104 MB WRITE_SIZE at 416 B/thread). Halving per-lane state to 8 elements
// (v/isyn/rf/th/cu = 40 regs + temps ~ 60) genuinely fits the 64-reg budget:
// zero spill AND full 32-waves/CU occupancy (2x the latency-hiding TLP).
//
// Layout: block = 512 threads = 8 waves = 4 rows x 2 halves. Wave (r,h) owns
// row b = 4*blk+r, elements d = h*512 + j*256 + 4*lane + i (j=0..1, i=0..3):
// float4-coalesced, cid(d) = (4*lane+i)&63 independent of h and j.
// Cluster sum: intra-wave shfl_xor(16,32) -> 64 partials per wave -> LDS
// (16 lanes x float4) -> 1 barrier -> lane k adds the two halves = cf[k]
// in a register -> 64-FMA dot via readlane broadcast (4 indep chains).
// cfbuf is double-buffered by t&1 so one barrier per timestep suffices.
// All cluster arithmetic is small-ints x 2^-4: exact, order-free.
__global__ __launch_bounds__(512) void snn_fwd(
    const float* __restrict__ cur_in,   // (T,B,D)
    const float* __restrict__ thr,      // (D,)
    const float* __restrict__ bm_raw,   // scalar
    const float* __restrict__ bs_raw,   // scalar
    const float* __restrict__ nw,       // (NC,NC)
    const float* __restrict__ gain,     // (NC,)
    float* __restrict__ out)            // spikes (T,B,D) then v_trace (T,B,D)
{
    __shared__ float WT[NCn * NCn];                 // WT[k*64+c] = sigmoid(nw[c][k])
    __shared__ __align__(16) float cfbuf[2][4][2][NCn];  // [t&1][row][half][cluster]

    const int tid  = threadIdx.x;
    const int lane = tid & 63;
    const int wv   = tid >> 6;
    const int r    = wv >> 1;           // row within block (0..3)
    const int h    = wv & 1;            // half of D (0..1)
    const int b    = (blockIdx.x << 2) + r;
    const int col0 = lane << 2;         // 4*lane
    const int hoff = (h << 9) + col0;   // h*512 + 4*lane

    // Issue t=0 input loads FIRST so their latency hides under W prep.
    float cu[8];
    {
        const size_t base0 = (size_t)b * Dn + hoff;
        #pragma unroll
        for (int j = 0; j < 2; ++j) {
            const float4 c4 = *reinterpret_cast<const float4*>(&cur_in[base0 + j * 256]);
            cu[j*4+0] = c4.x; cu[j*4+1] = c4.y; cu[j*4+2] = c4.z; cu[j*4+3] = c4.w;
        }
    }
    float th[8];
    #pragma unroll
    for (int j = 0; j < 2; ++j) {
        const float4 t4 = *reinterpret_cast<const float4*>(&thr[hoff + j * 256]);
        th[j*4+0] = t4.x; th[j*4+1] = t4.y; th[j*4+2] = t4.z; th[j*4+3] = t4.w;
    }

    // Per-block W prep: 8 sigmoids/thread, once.
    for (int e = tid; e < NCn * NCn; e += 512) {
        const int k = e >> 6, c = e & 63;
        WT[e] = sigm(nw[c * NCn + k]);
    }
    const float bm  = sigm(bm_raw[0]);
    const float bs  = sigm(bs_raw[0]);
    const float bm1 = 1.0f - bm;
    const float g   = gain[lane];

    float v[8], isyn[8], rf[8];
    #pragma unroll
    for (int e = 0; e < 8; ++e) { v[e] = 0.0f; isyn[e] = 0.0f; rf[e] = 0.0f; }

    __syncthreads();

    float* __restrict__ outS = out;
    float* __restrict__ outV = out + (size_t)Tn * Bn * Dn;

    #pragma unroll
    for (int t = 0; t < Tn; ++t) {
        const size_t base = ((size_t)t * Bn + b) * Dn + hoff;

        float cfp[4] = {0.0f, 0.0f, 0.0f, 0.0f};

        // Phase 1: state update + spike + store. cu[] is fully consumed here.
        #pragma unroll
        for (int j = 0; j < 2; ++j) {
            float s[4];
            #pragma unroll
            for (int i = 0; i < 4; ++i) {
                const int e = j * 4 + i;
                // i_syn = beta_s*i_syn + cur   (unfused mul+add, mirrors XLA)
                isyn[e] = __fadd_rn(__fmul_rn(bs, isyn[e]), cu[e]);
                // v_mem = refrac>0 ? V_RESET : beta_m*v + (1-beta_m)*i_syn
                float vn = __fadd_rn(__fmul_rn(bm, v[e]), __fmul_rn(bm1, isyn[e]));
                vn = (rf[e] > 0.0f) ? V_RESET : vn;
                const float sp = (vn >= th[e]) ? 1.0f : 0.0f;
                cfp[i] += sp;    // spike counts: small ints, exact in fp32
                s[i] = sp;
                // post-spike membrane + refractory update (off critical path)
                v[e]  = __fsub_rn(vn, __fmul_rn(sp, th[e]));
                rf[e] = (sp > 0.0f) ? REFRAC_T : fmaxf(rf[e] - 1.0f, 0.0f);
            }
            f32x4 s4; s4.x = s[0]; s4.y = s[1]; s4.z = s[2]; s4.w = s[3];
            f32x4 v4; v4.x = v[j*4+0]; v4.y = v[j*4+1]; v4.z = v[j*4+2]; v4.w = v[j*4+3];
            // Outputs are never re-read: nontemporal keeps input L3-resident.
            __builtin_nontemporal_store(s4, reinterpret_cast<f32x4*>(&outS[base + j * 256]));
            __builtin_nontemporal_store(v4, reinterpret_cast<f32x4*>(&outV[base + j * 256]));
        }

        // Phase 2: prefetch t+1's input into the now-free cu[] regs. Its
        // latency hides under phase 3 (reduce/dot/cascade) + wave TLP.
        if (t + 1 < Tn) {
            const size_t basen = ((size_t)(t + 1) * Bn + b) * Dn + hoff;
            #pragma unroll
            for (int j = 0; j < 2; ++j) {
                const float4 c4 = *reinterpret_cast<const float4*>(&cur_in[basen + j * 256]);
                cu[j*4+0] = c4.x; cu[j*4+1] = c4.y; cu[j*4+2] = c4.z; cu[j*4+3] = c4.w;
            }
        }

        // Phase 3a: intra-wave cluster partials (lanes l^16, l^32 share cid
        // set), *= 1/16 (exact). cfp[i] on lane l is this half's partial for
        // cluster 4*(l&15)+i.
        #pragma unroll
        for (int i = 0; i < 4; ++i) {
            cfp[i] += __shfl_xor(cfp[i], 16, 64);
            cfp[i] += __shfl_xor(cfp[i], 32, 64);
            cfp[i] *= V_SCALE;
        }
        // Phase 3b: publish this wave's 64 partials (lanes 0..15, float4 each)
        if (lane < 16) {
            f32x4 p; p.x = cfp[0]; p.y = cfp[1]; p.z = cfp[2]; p.w = cfp[3];
            *reinterpret_cast<f32x4*>(&cfbuf[t & 1][r][h][col0]) = p;
        }
        __syncthreads();
        // Phase 3c: combine halves; lane k now holds cf[k] for its row.
        const float total = cfbuf[t & 1][r][0][lane] + cfbuf[t & 1][r][1][lane];

        // neighbor[c=lane] = (sum_k cf[k] * W[c][k]) * gain[c]
        // cf[k] broadcast from lane k via v_readlane (SGPR fma operand).
        // 4 independent accumulator chains (dep depth 16 instead of 64).
        float a0 = 0.0f, a1 = 0.0f, a2 = 0.0f, a3 = 0.0f;
        #pragma unroll
        for (int k = 0; k < 64; k += 4) {
            a0 = fmaf(readlane_f(total, k+0), WT[(k+0) * 64 + lane], a0);
            a1 = fmaf(readlane_f(total, k+1), WT[(k+1) * 64 + lane], a1);
            a2 = fmaf(readlane_f(total, k+2), WT[(k+2) * 64 + lane], a2);
            a3 = fmaf(readlane_f(total, k+3), WT[(k+3) * 64 + lane], a3);
        }
        const float nb = __fmul_rn(__fadd_rn(__fadd_rn(a0, a1), __fadd_rn(a2, a3)), g);

        // cascade gather: this lane's 4 cids, then fold into i_syn for t+1
        #pragma unroll
        for (int i = 0; i < 4; ++i) {
            const float nbi = __shfl(nb, (col0 + i) & 63, 64);
            isyn[i]     = __fadd_rn(isyn[i],     nbi);
            isyn[4 + i] = __fadd_rn(isyn[4 + i], nbi);
        }
    }
}

extern "C" void kernel_launch(void* const* d_in, const int* in_sizes, int n_in,
                              void* d_out, int out_size, void* d_ws, size_t ws_size,
                              hipStream_t stream) {
    const float* cur_in = (const float*)d_in[0];
    const float* thr    = (const float*)d_in[1];
    const float* bm_raw = (const float*)d_in[2];
    const float* bs_raw = (const float*)d_in[3];
    const float* nw     = (const float*)d_in[4];
    const float* gain   = (const float*)d_in[5];
    float* out = (float*)d_out;

    // 4 rows per block, 2 waves per row -> B/4 = 1024 blocks of 512 threads.
    dim3 grid(Bn / 4), block(512);
    snn_fwd<<<grid, block, 0, stream>>>(cur_in, thr, bm_raw, bs_raw, nw, gain, out);
}